// Round 2
// baseline (554.362 us; speedup 1.0000x reference)
//
#include <hip/hip_runtime.h>
#include <hip/hip_bf16.h>

#define N_NODES 50000
#define N_EDGES 1000000
#define D_FEAT 512
#define F_ATTN 64
#define SLOPE 0.2f

typedef __attribute__((ext_vector_type(8))) short short8;
typedef __attribute__((ext_vector_type(4))) float floatx4;

// fp32 -> bf16 (round-to-nearest-even), bit trick; inputs are finite randoms.
static __device__ __forceinline__ short f2bf(float x) {
    unsigned u = __float_as_uint(x);
    unsigned r = (u + 0x7FFFu + ((u >> 16) & 1u)) >> 16;
    return (short)r;
}

static __device__ __forceinline__ short8 cvt8(const float* __restrict__ p) {
    float4 lo = *(const float4*)p;
    float4 hi = *(const float4*)(p + 4);
    short8 r;
    r[0] = f2bf(lo.x); r[1] = f2bf(lo.y); r[2] = f2bf(lo.z); r[3] = f2bf(lo.w);
    r[4] = f2bf(hi.x); r[5] = f2bf(hi.y); r[6] = f2bf(hi.z); r[7] = f2bf(hi.w);
    return r;
}

// ---------------- Projection: z[n][f] = (type?d_sim:m_sim)[n] @ (type?Wd:Wm).T
// fp32 inputs converted to bf16 in-register, MFMA 16x16x32 bf16, fp32 accum.
// Wave handles 16 nodes x 64 feats; both type variants computed, selected at
// epilogue (tiles mix types; W re-reads are L1/L2-resident, sims dominate).
__global__ __launch_bounds__(256) void proj_kernel(
    const float* __restrict__ d_sim,
    const float* __restrict__ m_sim,
    const float* __restrict__ Wd,
    const float* __restrict__ Wm,
    const int* __restrict__ node_type,
    __hip_bfloat16* __restrict__ z)
{
    const int wave   = threadIdx.x >> 6;
    const int lane   = threadIdx.x & 63;
    const int laneLo = lane & 15;
    const int quad   = lane >> 4;
    const int nodeBase = blockIdx.x * 64 + wave * 16;

    floatx4 accD[4], accM[4];
    #pragma unroll
    for (int nt = 0; nt < 4; nt++) {
        accD[nt] = (floatx4){0.f, 0.f, 0.f, 0.f};
        accM[nt] = (floatx4){0.f, 0.f, 0.f, 0.f};
    }

    int arow = nodeBase + laneLo;
    if (arow >= N_NODES) arow = N_NODES - 1;   // clamp; stores guarded below
    const float* aDp = d_sim + (size_t)arow * D_FEAT + quad * 8;
    const float* aMp = m_sim + (size_t)arow * D_FEAT + quad * 8;
    const float* bDp = Wd + (size_t)laneLo * D_FEAT + quad * 8;
    const float* bMp = Wm + (size_t)laneLo * D_FEAT + quad * 8;

    for (int k0 = 0; k0 < D_FEAT; k0 += 32) {
        short8 aD = cvt8(aDp + k0);
        short8 aM = cvt8(aMp + k0);
        #pragma unroll
        for (int nt = 0; nt < 4; nt++) {
            short8 bD = cvt8(bDp + (size_t)nt * 16 * D_FEAT + k0);
            short8 bM = cvt8(bMp + (size_t)nt * 16 * D_FEAT + k0);
            accD[nt] = __builtin_amdgcn_mfma_f32_16x16x32_bf16(aD, bD, accD[nt], 0, 0, 0);
            accM[nt] = __builtin_amdgcn_mfma_f32_16x16x32_bf16(aM, bM, accM[nt], 0, 0, 0);
        }
    }

    // C/D layout: col = lane&15 (feature), row = quad*4 + reg (node)
    #pragma unroll
    for (int reg = 0; reg < 4; reg++) {
        int node = nodeBase + quad * 4 + reg;
        if (node < N_NODES) {
            int isD = (node_type[node] == 1);
            #pragma unroll
            for (int nt = 0; nt < 4; nt++) {
                float v = isD ? accD[nt][reg] : accM[nt][reg];
                z[(size_t)node * F_ATTN + nt * 16 + laneLo] =
                    __hip_bfloat16(__float2bfloat16(v));
            }
        }
    }
}

// ---------------- Per-node attention scalars: s1 = z . Wa[0:64], s2 = z . Wa[64:128]
__global__ __launch_bounds__(256) void attn_s_kernel(
    const __hip_bfloat16* __restrict__ z,
    const float* __restrict__ Wa,
    float* __restrict__ s1, float* __restrict__ s2)
{
    int node = blockIdx.x * 4 + (threadIdx.x >> 6);
    int lane = threadIdx.x & 63;
    float zv = __bfloat162float(z[(size_t)node * F_ATTN + lane]);
    float p1 = zv * Wa[lane];
    float p2 = zv * Wa[F_ATTN + lane];
    #pragma unroll
    for (int off = 32; off; off >>= 1) {
        p1 += __shfl_xor(p1, off);
        p2 += __shfl_xor(p2, off);
    }
    if (lane == 0) { s1[node] = p1; s2[node] = p2; }
}

// ---------------- CSR build: histogram over dst
__global__ __launch_bounds__(256) void hist_kernel(
    const int* __restrict__ edge_dst, int* __restrict__ counts)
{
    int e = blockIdx.x * 256 + threadIdx.x;
    if (e < N_EDGES) atomicAdd(&counts[edge_dst[e]], 1);
}

// ---------------- Single-block exclusive scan of counts -> offsets[N+1]
__global__ __launch_bounds__(1024) void scan_kernel(
    const int* __restrict__ counts, int* __restrict__ offsets)
{
    __shared__ int lds[1024];
    const int t = threadIdx.x;
    const int CH = (N_NODES + 1023) / 1024;  // 49
    int start = t * CH;
    int end   = start + CH; if (end > N_NODES) end = N_NODES;
    if (start > N_NODES) start = N_NODES;

    int s = 0;
    for (int i = start; i < end; i++) s += counts[i];
    lds[t] = s;
    __syncthreads();
    for (int off = 1; off < 1024; off <<= 1) {
        int u = 0;
        if (t >= off) u = lds[t - off];
        __syncthreads();
        if (t >= off) lds[t] += u;
        __syncthreads();
    }
    int run = (t > 0) ? lds[t - 1] : 0;   // exclusive base
    for (int i = start; i < end; i++) { offsets[i] = run; run += counts[i]; }
    if (t == 1023) offsets[N_NODES] = run;  // = total edges
}

// ---------------- Scatter edge srcs into CSR order
__global__ __launch_bounds__(256) void scatter_kernel(
    const int* __restrict__ edge_src, const int* __restrict__ edge_dst,
    const int* __restrict__ offsets, int* __restrict__ cursor,
    int* __restrict__ csr_src)
{
    int e = blockIdx.x * 256 + threadIdx.x;
    if (e < N_EDGES) {
        int d = edge_dst[e];
        int pos = offsets[d] + atomicAdd(&cursor[d], 1);
        csr_src[pos] = edge_src[e];
    }
}

// ---------------- Aggregation: one wave per dst node, lane = feature.
// Online softmax over incoming edges, fused weighted sum, elu, fp32 store.
__global__ __launch_bounds__(256) void agg_kernel(
    const int* __restrict__ offsets, const int* __restrict__ csr_src,
    const float* __restrict__ s1, const float* __restrict__ s2,
    const __hip_bfloat16* __restrict__ z, float* __restrict__ out)
{
    int node = blockIdx.x * 4 + (threadIdx.x >> 6);
    int lane = threadIdx.x & 63;
    int beg = offsets[node], end = offsets[node + 1];
    float s2n = s2[node];

    float m = -INFINITY, l = 0.f, h = 0.f;
    for (int base = beg; base < end; base += 64) {
        int idx = base + lane;
        int src = 0; float e = -INFINITY;
        if (idx < end) {
            src = csr_src[idx];
            float t = s1[src] + s2n;
            e = (t > 0.f) ? t : SLOPE * t;   // leaky_relu
        }
        // chunk max -> update running max, rescale
        float cm = e;
        #pragma unroll
        for (int off = 32; off; off >>= 1) cm = fmaxf(cm, __shfl_xor(cm, off));
        float nm = fmaxf(m, cm);
        float scale = (m == -INFINITY) ? 0.f : __expf(m - nm);
        h *= scale; l *= scale;

        int cnt = end - base; if (cnt > 64) cnt = 64;
        for (int j = 0; j < cnt; j++) {
            float ej = __shfl(e, j);
            int   sj = __shfl(src, j);
            float w  = __expf(ej - nm);
            l += w;
            h += w * __bfloat162float(z[(size_t)sj * F_ATTN + lane]);
        }
        m = nm;
    }
    float hv = (end > beg) ? h / l : 0.f;
    float o  = (hv > 0.f) ? hv : (__expf(hv) - 1.f);   // elu
    out[(size_t)node * F_ATTN + lane] = o;
}

extern "C" void kernel_launch(void* const* d_in, const int* in_sizes, int n_in,
                              void* d_out, int out_size, void* d_ws, size_t ws_size,
                              hipStream_t stream) {
    const float* d_sim = (const float*)d_in[0];
    const float* m_sim = (const float*)d_in[1];
    const float* Wd    = (const float*)d_in[2];
    const float* Wm    = (const float*)d_in[3];
    const float* Wa    = (const float*)d_in[4];
    const int* node_type = (const int*)d_in[5];
    const int* edge_src  = (const int*)d_in[6];
    const int* edge_dst  = (const int*)d_in[7];
    float* out = (float*)d_out;

    char* ws = (char*)d_ws;
    // ws layout (bytes):
    __hip_bfloat16* z    = (__hip_bfloat16*)(ws + 0);          // 6,400,000
    float* s1            = (float*)(ws + 6400000);             //   200,000
    float* s2            = (float*)(ws + 6600000);             //   200,000
    int*   counts        = (int*)  (ws + 6800000);             //   200,000
    int*   cursor        = (int*)  (ws + 7000000);             //   200,000 (adjacent to counts)
    int*   offsets       = (int*)  (ws + 7200000);             //   200,016
    int*   csr_src       = (int*)  (ws + 7400016);             // 4,000,000

    // zero counts + cursor in one shot (they are adjacent)
    hipMemsetAsync(counts, 0, 2 * N_NODES * sizeof(int), stream);

    proj_kernel<<<(N_NODES + 63) / 64, 256, 0, stream>>>(d_sim, m_sim, Wd, Wm, node_type, z);
    attn_s_kernel<<<N_NODES / 4, 256, 0, stream>>>(z, Wa, s1, s2);
    hist_kernel<<<(N_EDGES + 255) / 256, 256, 0, stream>>>(edge_dst, counts);
    scan_kernel<<<1, 1024, 0, stream>>>(counts, offsets);
    scatter_kernel<<<(N_EDGES + 255) / 256, 256, 0, stream>>>(edge_src, edge_dst, offsets, cursor, csr_src);
    agg_kernel<<<N_NODES / 4, 256, 0, stream>>>(offsets, csr_src, s1, s2, z, out);
}

// Round 3
// 492.480 us; speedup vs baseline: 1.1257x; 1.1257x over previous
//
#include <hip/hip_runtime.h>
#include <hip/hip_bf16.h>

#define N_NODES 50000
#define N_EDGES 1000000
#define D_FEAT 512
#define F_ATTN 64
#define SLOPE 0.2f

typedef __attribute__((ext_vector_type(8))) short short8;
typedef __attribute__((ext_vector_type(4))) float floatx4;

// fp32 -> bf16 (round-to-nearest-even), bit trick; inputs are finite randoms.
static __device__ __forceinline__ short f2bf(float x) {
    unsigned u = __float_as_uint(x);
    unsigned r = (u + 0x7FFFu + ((u >> 16) & 1u)) >> 16;
    return (short)r;
}

// ---------------- One-time W convert: Wd,Wm (64x512 fp32) -> Wb (128x512 bf16)
__global__ __launch_bounds__(256) void wcvt_kernel(
    const float* __restrict__ Wd, const float* __restrict__ Wm,
    short* __restrict__ Wb)
{
    int i = blockIdx.x * 256 + threadIdx.x;           // 0 .. 65535
    int half = F_ATTN * D_FEAT;                        // 32768
    float v = (i < half) ? Wd[i] : Wm[i - half];
    Wb[i] = f2bf(v);
}

// ---------------- Projection + fused attention scalars.
// z[n] = (type?d_sim:m_sim)[n] @ (type?Wd:Wm).T   (bf16 MFMA, fp32 accum)
// s1[n] = z[n].Wa[0:64], s2[n] = z[n].Wa[64:128]  (from fp32 accumulators)
// A row pointer is type-selected (reads only the needed sim matrix).
// Register double-buffer prefetch of next A chunk hides HBM latency.
__global__ __launch_bounds__(256) void proj_kernel(
    const float* __restrict__ d_sim,
    const float* __restrict__ m_sim,
    const short* __restrict__ Wb,
    const float* __restrict__ Wa,
    const int* __restrict__ node_type,
    __hip_bfloat16* __restrict__ z,
    float* __restrict__ s1, float* __restrict__ s2)
{
    const int wave   = threadIdx.x >> 6;
    const int lane   = threadIdx.x & 63;
    const int laneLo = lane & 15;
    const int quad   = lane >> 4;
    const int nodeBase = blockIdx.x * 64 + wave * 16;

    floatx4 accD[4], accM[4];
    #pragma unroll
    for (int nt = 0; nt < 4; nt++) {
        accD[nt] = (floatx4){0.f, 0.f, 0.f, 0.f};
        accM[nt] = (floatx4){0.f, 0.f, 0.f, 0.f};
    }

    int arow = nodeBase + laneLo;
    if (arow >= N_NODES) arow = N_NODES - 1;   // clamp; stores guarded below
    const float* aPtr = ((node_type[arow] == 1) ? d_sim : m_sim)
                        + (size_t)arow * D_FEAT + quad * 8;
    const short* bbase = Wb + (size_t)laneLo * D_FEAT + quad * 8;

    float4 a0 = *(const float4*)(aPtr);
    float4 a1 = *(const float4*)(aPtr + 4);
    for (int k0 = 0; k0 < D_FEAT; k0 += 32) {
        float4 n0, n1;
        if (k0 + 32 < D_FEAT) {                  // prefetch next A chunk
            n0 = *(const float4*)(aPtr + k0 + 32);
            n1 = *(const float4*)(aPtr + k0 + 36);
        }
        short8 a;
        a[0] = f2bf(a0.x); a[1] = f2bf(a0.y); a[2] = f2bf(a0.z); a[3] = f2bf(a0.w);
        a[4] = f2bf(a1.x); a[5] = f2bf(a1.y); a[6] = f2bf(a1.z); a[7] = f2bf(a1.w);
        #pragma unroll
        for (int nt = 0; nt < 4; nt++) {
            short8 bD = *(const short8*)(bbase + (size_t)(nt * 16) * D_FEAT + k0);
            short8 bM = *(const short8*)(bbase + (size_t)(64 + nt * 16) * D_FEAT + k0);
            accD[nt] = __builtin_amdgcn_mfma_f32_16x16x32_bf16(a, bD, accD[nt], 0, 0, 0);
            accM[nt] = __builtin_amdgcn_mfma_f32_16x16x32_bf16(a, bM, accM[nt], 0, 0, 0);
        }
        a0 = n0; a1 = n1;
    }

    float wa1[4], wa2[4];
    #pragma unroll
    for (int nt = 0; nt < 4; nt++) {
        wa1[nt] = Wa[nt * 16 + laneLo];
        wa2[nt] = Wa[F_ATTN + nt * 16 + laneLo];
    }

    // C/D layout: col = lane&15 (feature), row = quad*4 + reg (node)
    #pragma unroll
    for (int reg = 0; reg < 4; reg++) {
        int node = nodeBase + quad * 4 + reg;
        bool ok = node < N_NODES;
        int isD = ok ? (node_type[node] == 1) : 0;
        float p1 = 0.f, p2 = 0.f;
        #pragma unroll
        for (int nt = 0; nt < 4; nt++) {
            float v = isD ? accD[nt][reg] : accM[nt][reg];
            if (ok) z[(size_t)node * F_ATTN + nt * 16 + laneLo] = __float2bfloat16(v);
            p1 += v * wa1[nt];
            p2 += v * wa2[nt];
        }
        // reduce across the 16 laneLo lanes (stays within quad for offsets <16)
        #pragma unroll
        for (int off = 8; off; off >>= 1) {
            p1 += __shfl_xor(p1, off);
            p2 += __shfl_xor(p2, off);
        }
        if (ok && laneLo == 0) { s1[node] = p1; s2[node] = p2; }
    }
}

// ---------------- CSR build: histogram over dst
__global__ __launch_bounds__(256) void hist_kernel(
    const int* __restrict__ edge_dst, int* __restrict__ counts)
{
    int e = blockIdx.x * 256 + threadIdx.x;
    if (e < N_EDGES) atomicAdd(&counts[edge_dst[e]], 1);
}

// ---------------- Single-block exclusive scan of counts -> offsets[N+1]
__global__ __launch_bounds__(1024) void scan_kernel(
    const int* __restrict__ counts, int* __restrict__ offsets)
{
    __shared__ int lds[1024];
    const int t = threadIdx.x;
    const int CH = (N_NODES + 1023) / 1024;  // 49
    int start = t * CH;
    int end   = start + CH; if (end > N_NODES) end = N_NODES;
    if (start > N_NODES) start = N_NODES;

    int s = 0;
    for (int i = start; i < end; i++) s += counts[i];
    lds[t] = s;
    __syncthreads();
    for (int off = 1; off < 1024; off <<= 1) {
        int u = 0;
        if (t >= off) u = lds[t - off];
        __syncthreads();
        if (t >= off) lds[t] += u;
        __syncthreads();
    }
    int run = (t > 0) ? lds[t - 1] : 0;   // exclusive base
    for (int i = start; i < end; i++) { offsets[i] = run; run += counts[i]; }
    if (t == 1023) offsets[N_NODES] = run;  // = total edges
}

// ---------------- Scatter: CSR order srcs + fused edge logit (leaky_relu).
// Reuses counts as the cursor (atomicSub drains it back to zero).
__global__ __launch_bounds__(256) void scatter_kernel(
    const int* __restrict__ edge_src, const int* __restrict__ edge_dst,
    const int* __restrict__ offsets, int* __restrict__ counts,
    const float* __restrict__ s1, const float* __restrict__ s2,
    int* __restrict__ csr_src, float* __restrict__ csr_e)
{
    int e = blockIdx.x * 256 + threadIdx.x;
    if (e < N_EDGES) {
        int d = edge_dst[e];
        int s = edge_src[e];
        float t = s1[s] + s2[d];
        float ev = (t > 0.f) ? t : SLOPE * t;
        int old = atomicSub(&counts[d], 1);
        int pos = offsets[d] + old - 1;
        csr_src[pos] = s;
        csr_e[pos]   = ev;
    }
}

// ---------------- Aggregation: one wave per dst node, lane = feature.
// Two-pass softmax (max, then weights) with precomputed logits; the
// per-edge z-row gather loop is unrolled x4 for outstanding loads.
__global__ __launch_bounds__(256) void agg_kernel(
    const int* __restrict__ offsets, const int* __restrict__ csr_src,
    const float* __restrict__ csr_e,
    const __hip_bfloat16* __restrict__ z, float* __restrict__ out)
{
    int node = blockIdx.x * 4 + (threadIdx.x >> 6);
    int lane = threadIdx.x & 63;
    int beg = offsets[node], end = offsets[node + 1];

    // pass 1: segment max (edge-parallel)
    float m = -INFINITY;
    for (int base = beg; base < end; base += 64) {
        int idx = base + lane;
        if (idx < end) m = fmaxf(m, csr_e[idx]);
    }
    #pragma unroll
    for (int off = 32; off; off >>= 1) m = fmaxf(m, __shfl_xor(m, off));

    // pass 2: weights + weighted feature aggregation
    float l = 0.f, h = 0.f;
    for (int base = beg; base < end; base += 64) {
        int idx = base + lane;
        float w = 0.f; int src = 0;
        if (idx < end) {
            w   = __expf(csr_e[idx] - m);
            src = csr_src[idx];
        }
        l += w;
        int cnt = end - base; if (cnt > 64) cnt = 64;
        for (int j = 0; j < cnt; j += 4) {
            #pragma unroll
            for (int u = 0; u < 4; u++) {       // lanes >= cnt have w=0, src=0
                float wj = __shfl(w, j + u);
                int   sj = __shfl(src, j + u);
                h += wj * __bfloat162float(z[(size_t)sj * F_ATTN + lane]);
            }
        }
    }
    #pragma unroll
    for (int off = 32; off; off >>= 1) l += __shfl_xor(l, off);

    float hv = (end > beg) ? h / l : 0.f;
    float o  = (hv > 0.f) ? hv : (__expf(hv) - 1.f);   // elu
    out[(size_t)node * F_ATTN + lane] = o;
}

extern "C" void kernel_launch(void* const* d_in, const int* in_sizes, int n_in,
                              void* d_out, int out_size, void* d_ws, size_t ws_size,
                              hipStream_t stream) {
    const float* d_sim = (const float*)d_in[0];
    const float* m_sim = (const float*)d_in[1];
    const float* Wd    = (const float*)d_in[2];
    const float* Wm    = (const float*)d_in[3];
    const float* Wa    = (const float*)d_in[4];
    const int* node_type = (const int*)d_in[5];
    const int* edge_src  = (const int*)d_in[6];
    const int* edge_dst  = (const int*)d_in[7];
    float* out = (float*)d_out;

    char* ws = (char*)d_ws;
    // ws layout (bytes):
    __hip_bfloat16* z  = (__hip_bfloat16*)(ws + 0);        //  6,400,000
    float* s1          = (float*)(ws + 6400000);           //    200,000
    float* s2          = (float*)(ws + 6600000);           //    200,000
    int*   counts      = (int*)  (ws + 6800000);           //    200,000
    int*   offsets     = (int*)  (ws + 7000000);           //    200,016
    int*   csr_src     = (int*)  (ws + 7200016);           //  4,000,000
    float* csr_e       = (float*)(ws + 11200016);          //  4,000,000
    short* Wb          = (short*)(ws + 15200016);          //    131,072  (16B aligned)

    hipMemsetAsync(counts, 0, N_NODES * sizeof(int), stream);

    wcvt_kernel<<<(2 * F_ATTN * D_FEAT) / 256, 256, 0, stream>>>(Wd, Wm, Wb);
    proj_kernel<<<(N_NODES + 63) / 64, 256, 0, stream>>>(
        d_sim, m_sim, Wb, Wa, node_type, z, s1, s2);
    hist_kernel<<<(N_EDGES + 255) / 256, 256, 0, stream>>>(edge_dst, counts);
    scan_kernel<<<1, 1024, 0, stream>>>(counts, offsets);
    scatter_kernel<<<(N_EDGES + 255) / 256, 256, 0, stream>>>(
        edge_src, edge_dst, offsets, counts, s1, s2, csr_src, csr_e);
    agg_kernel<<<N_NODES / 4, 256, 0, stream>>>(offsets, csr_src, csr_e, z, out);
}

// Round 4
// 433.053 us; speedup vs baseline: 1.2801x; 1.1372x over previous
//
#include <hip/hip_runtime.h>
#include <hip/hip_bf16.h>

#define N_NODES 50000
#define N_EDGES 1000000
#define D_FEAT 512
#define F_ATTN 64
#define SLOPE 0.2f

typedef __attribute__((ext_vector_type(8))) short short8;
typedef __attribute__((ext_vector_type(4))) float floatx4;

// fp32 -> bf16 (round-to-nearest-even), bit trick; inputs are finite randoms.
static __device__ __forceinline__ short f2bf(float x) {
    unsigned u = __float_as_uint(x);
    unsigned r = (u + 0x7FFFu + ((u >> 16) & 1u)) >> 16;
    return (short)r;
}

static __device__ __forceinline__ short8 cvt2(float4 x, float4 y) {
    short8 r;
    r[0] = f2bf(x.x); r[1] = f2bf(x.y); r[2] = f2bf(x.z); r[3] = f2bf(x.w);
    r[4] = f2bf(y.x); r[5] = f2bf(y.y); r[6] = f2bf(y.z); r[7] = f2bf(y.w);
    return r;
}

// async global->LDS, 16B per lane. LDS dest = wave-uniform base + lane*16.
static __device__ __forceinline__ void g2lds16(const void* g, void* l) {
    __builtin_amdgcn_global_load_lds(
        (const __attribute__((address_space(1))) void*)g,
        (__attribute__((address_space(3))) void*)l, 16, 0, 0);
}

// ---------------- One-time W convert: Wd,Wm (64x512 fp32) -> Wb (128x512 bf16)
__global__ __launch_bounds__(256) void wcvt_kernel(
    const float* __restrict__ Wd, const float* __restrict__ Wm,
    short* __restrict__ Wb)
{
    int i = blockIdx.x * 256 + threadIdx.x;           // 0 .. 65535
    int half = F_ATTN * D_FEAT;                        // 32768
    float v = (i < half) ? Wd[i] : Wm[i - half];
    Wb[i] = f2bf(v);
}

// ---------------- Projection + fused attention scalars (m97-style LDS GEMM).
// Block = 64 rows x 64 feats, K=512 in 8 tiles of BK=64. Double-buffered LDS:
//   A tile: 64 rows x 64 cols fp32 (16KB), type-selected row gather
//   B tile: 128 rows (Wd|Wm) x 64 cols bf16 (16KB)
// Both staged via global_load_lds width=16; 16B chunks XOR-swizzled by row
// (slot s holds logical chunk s^(row&7)) so strided ds_read_b128 fragment
// reads are bank-conflict-free. Dual-type MFMA, per-row select at epilogue,
// fused s1/s2 = z . Wa halves.
__global__ __launch_bounds__(256) void proj_kernel(
    const float* __restrict__ d_sim,
    const float* __restrict__ m_sim,
    const short* __restrict__ Wb,
    const float* __restrict__ Wa,
    const int* __restrict__ node_type,
    __hip_bfloat16* __restrict__ z,
    float* __restrict__ s1, float* __restrict__ s2)
{
    __shared__ char smem[65536];   // 2 bufs x (16KB A + 16KB B)

    const int w      = threadIdx.x >> 6;
    const int lane   = threadIdx.x & 63;
    const int laneLo = lane & 15;
    const int quad   = lane >> 4;
    const int nodeBase = blockIdx.x * 64;

    // ---- per-lane global staging pointers (computed once) ----
    // A: instr i stages tile rows w*16+i*4 .. +3; lane -> row += lane>>4,
    //    slot = lane&15, logical chunk = slot ^ (row&7)  (16B = 4 floats)
    const float* aP[4];
    #pragma unroll
    for (int i = 0; i < 4; i++) {
        int r = w * 16 + i * 4 + (lane >> 4);
        int arow = nodeBase + r; if (arow >= N_NODES) arow = N_NODES - 1;
        int lc = (lane & 15) ^ (r & 7);
        const float* src = (node_type[arow] == 1) ? d_sim : m_sim;
        aP[i] = src + (size_t)arow * D_FEAT + (lc << 2);
    }
    // B: instr i stages Wb rows (w*4+i)*8 .. +7; lane -> row += lane>>3,
    //    slot = lane&7, logical chunk = slot ^ (row&7)  (16B = 8 shorts)
    const short* bP[4];
    #pragma unroll
    for (int i = 0; i < 4; i++) {
        int r = (w * 4 + i) * 8 + (lane >> 3);
        int lc = (lane & 7) ^ (r & 7);
        bP[i] = Wb + (size_t)r * D_FEAT + (lc << 3);
    }

    floatx4 accD[4], accM[4];
    #pragma unroll
    for (int nt = 0; nt < 4; nt++) {
        accD[nt] = (floatx4){0.f, 0.f, 0.f, 0.f};
        accM[nt] = (floatx4){0.f, 0.f, 0.f, 0.f};
    }

    // ---- stage tile 0 ----
    {
        char* b0 = smem;
        #pragma unroll
        for (int i = 0; i < 4; i++)
            g2lds16(aP[i], b0 + (w * 16 + i * 4) * 256);
        #pragma unroll
        for (int i = 0; i < 4; i++)
            g2lds16(bP[i], b0 + 16384 + (w * 4 + i) * 1024);
    }
    __syncthreads();

    const int rA  = w * 16 + laneLo;
    const int rx  = laneLo & 7;           // (row&7) for both A and B fragments

    for (int t = 0; t < 8; t++) {
        if (t < 7) {
            char* nb = smem + ((t + 1) & 1) * 32768;
            int k0 = (t + 1) * 64;
            #pragma unroll
            for (int i = 0; i < 4; i++)
                g2lds16(aP[i] + k0, nb + (w * 16 + i * 4) * 256);
            #pragma unroll
            for (int i = 0; i < 4; i++)
                g2lds16(bP[i] + k0, nb + 16384 + (w * 4 + i) * 1024);
        }
        const char* cb = smem + (t & 1) * 32768;
        #pragma unroll
        for (int ks = 0; ks < 2; ks++) {
            int c0 = ks * 8 + quad * 2;
            float4 a0 = *(const float4*)(cb + rA * 256 + ((c0 ^ rx) << 4));
            float4 a1 = *(const float4*)(cb + rA * 256 + (((c0 + 1) ^ rx) << 4));
            short8 a = cvt2(a0, a1);
            int ch = ks * 4 + quad;
            int sl = (ch ^ rx) << 4;
            #pragma unroll
            for (int nt = 0; nt < 4; nt++) {
                const char* rowD = cb + 16384 + (nt * 16 + laneLo) * 128;
                short8 bD = *(const short8*)(rowD + sl);
                short8 bM = *(const short8*)(rowD + 64 * 128 + sl);
                accD[nt] = __builtin_amdgcn_mfma_f32_16x16x32_bf16(a, bD, accD[nt], 0, 0, 0);
                accM[nt] = __builtin_amdgcn_mfma_f32_16x16x32_bf16(a, bM, accM[nt], 0, 0, 0);
            }
        }
        __syncthreads();
    }

    float wa1[4], wa2[4];
    #pragma unroll
    for (int nt = 0; nt < 4; nt++) {
        wa1[nt] = Wa[nt * 16 + laneLo];
        wa2[nt] = Wa[F_ATTN + nt * 16 + laneLo];
    }

    // C/D layout: col = lane&15 (feature), row = quad*4 + reg (node)
    #pragma unroll
    for (int reg = 0; reg < 4; reg++) {
        int node = nodeBase + w * 16 + quad * 4 + reg;
        bool ok = node < N_NODES;
        int isD = ok ? (node_type[node] == 1) : 0;
        float p1 = 0.f, p2 = 0.f;
        #pragma unroll
        for (int nt = 0; nt < 4; nt++) {
            float v = isD ? accD[nt][reg] : accM[nt][reg];
            if (ok) z[(size_t)node * F_ATTN + nt * 16 + laneLo] = __float2bfloat16(v);
            p1 += v * wa1[nt];
            p2 += v * wa2[nt];
        }
        #pragma unroll
        for (int off = 8; off; off >>= 1) {   // reduce across 16 laneLo lanes
            p1 += __shfl_xor(p1, off);
            p2 += __shfl_xor(p2, off);
        }
        if (ok && laneLo == 0) { s1[node] = p1; s2[node] = p2; }
    }
}

// ---------------- CSR build: histogram over dst
__global__ __launch_bounds__(256) void hist_kernel(
    const int* __restrict__ edge_dst, int* __restrict__ counts)
{
    int e = blockIdx.x * 256 + threadIdx.x;
    if (e < N_EDGES) atomicAdd(&counts[edge_dst[e]], 1);
}

// ---------------- Single-block exclusive scan of counts -> offsets[N+1]
__global__ __launch_bounds__(1024) void scan_kernel(
    const int* __restrict__ counts, int* __restrict__ offsets)
{
    __shared__ int lds[1024];
    const int t = threadIdx.x;
    const int CH = (N_NODES + 1023) / 1024;  // 49
    int start = t * CH;
    int end   = start + CH; if (end > N_NODES) end = N_NODES;
    if (start > N_NODES) start = N_NODES;

    int s = 0;
    for (int i = start; i < end; i++) s += counts[i];
    lds[t] = s;
    __syncthreads();
    for (int off = 1; off < 1024; off <<= 1) {
        int u = 0;
        if (t >= off) u = lds[t - off];
        __syncthreads();
        if (t >= off) lds[t] += u;
        __syncthreads();
    }
    int run = (t > 0) ? lds[t - 1] : 0;   // exclusive base
    for (int i = start; i < end; i++) { offsets[i] = run; run += counts[i]; }
    if (t == 1023) offsets[N_NODES] = run;  // = total edges
}

// ---------------- Scatter: CSR srcs + precomputed softmax numerator
// exp(leaky_relu(s1[src]+s2[dst])). No segment max needed: logits are
// O(few) by construction (normalized weights), exp cannot overflow, and
// softmax ratios are identical without the max shift.
// Reuses counts as cursor (atomicSub drains it back to zero).
__global__ __launch_bounds__(256) void scatter_kernel(
    const int* __restrict__ edge_src, const int* __restrict__ edge_dst,
    const int* __restrict__ offsets, int* __restrict__ counts,
    const float* __restrict__ s1, const float* __restrict__ s2,
    int* __restrict__ csr_src, float* __restrict__ csr_e)
{
    int e = blockIdx.x * 256 + threadIdx.x;
    if (e < N_EDGES) {
        int d = edge_dst[e];
        int s = edge_src[e];
        float t = s1[s] + s2[d];
        float ev = (t > 0.f) ? t : SLOPE * t;
        int old = atomicSub(&counts[d], 1);
        int pos = offsets[d] + old - 1;
        csr_src[pos] = s;
        csr_e[pos]   = __expf(ev);
    }
}

// ---------------- Aggregation: one wave per dst node, lane = feature.
// Weights precomputed in scatter. Per-wave LDS staging of (w,src) kills the
// shfl dependency chain; 8-deep unroll keeps 8 z-row gathers outstanding.
__global__ __launch_bounds__(256) void agg_kernel(
    const int* __restrict__ offsets, const int* __restrict__ csr_src,
    const float* __restrict__ csr_e,
    const __hip_bfloat16* __restrict__ z, float* __restrict__ out)
{
    __shared__ float sW[256];
    __shared__ int   sS[256];
    int wv   = threadIdx.x >> 6;
    int lane = threadIdx.x & 63;
    int node = blockIdx.x * 4 + wv;
    int beg = offsets[node], end = offsets[node + 1];
    int wbase = wv * 64;

    float l = 0.f, h = 0.f;
    for (int base = beg; base < end; base += 64) {
        int idx = base + lane;
        float wgt = 0.f; int src = 0;
        if (idx < end) { wgt = csr_e[idx]; src = csr_src[idx]; }
        l += wgt;
        sW[wbase + lane] = wgt;
        sS[wbase + lane] = src;
        int cnt = end - base; if (cnt > 64) cnt = 64;
        for (int j = 0; j < cnt; j += 8) {
            #pragma unroll
            for (int u = 0; u < 8; u++) {     // slots >= cnt have w=0 (pad)
                float wj = sW[wbase + j + u];
                int   sj = sS[wbase + j + u];
                h += wj * __bfloat162float(z[(size_t)sj * F_ATTN + lane]);
            }
        }
    }
    #pragma unroll
    for (int off = 32; off; off >>= 1) l += __shfl_xor(l, off);

    float hv = (end > beg) ? h / l : 0.f;
    float o  = (hv > 0.f) ? hv : (__expf(hv) - 1.f);   // elu
    out[(size_t)node * F_ATTN + lane] = o;
}

extern "C" void kernel_launch(void* const* d_in, const int* in_sizes, int n_in,
                              void* d_out, int out_size, void* d_ws, size_t ws_size,
                              hipStream_t stream) {
    const float* d_sim = (const float*)d_in[0];
    const float* m_sim = (const float*)d_in[1];
    const float* Wd    = (const float*)d_in[2];
    const float* Wm    = (const float*)d_in[3];
    const float* Wa    = (const float*)d_in[4];
    const int* node_type = (const int*)d_in[5];
    const int* edge_src  = (const int*)d_in[6];
    const int* edge_dst  = (const int*)d_in[7];
    float* out = (float*)d_out;

    char* ws = (char*)d_ws;
    // ws layout (bytes):
    __hip_bfloat16* z  = (__hip_bfloat16*)(ws + 0);        //  6,400,000
    float* s1          = (float*)(ws + 6400000);           //    200,000
    float* s2          = (float*)(ws + 6600000);           //    200,000
    int*   counts      = (int*)  (ws + 6800000);           //    200,000
    int*   offsets     = (int*)  (ws + 7000000);           //    200,016
    int*   csr_src     = (int*)  (ws + 7200016);           //  4,000,000
    float* csr_e       = (float*)(ws + 11200016);          //  4,000,000
    short* Wb          = (short*)(ws + 15200016);          //    131,072  (16B aligned)

    hipMemsetAsync(counts, 0, N_NODES * sizeof(int), stream);

    wcvt_kernel<<<(2 * F_ATTN * D_FEAT) / 256, 256, 0, stream>>>(Wd, Wm, Wb);
    proj_kernel<<<(N_NODES + 63) / 64, 256, 0, stream>>>(
        d_sim, m_sim, Wb, Wa, node_type, z, s1, s2);
    hist_kernel<<<(N_EDGES + 255) / 256, 256, 0, stream>>>(edge_dst, counts);
    scan_kernel<<<1, 1024, 0, stream>>>(counts, offsets);
    scatter_kernel<<<(N_EDGES + 255) / 256, 256, 0, stream>>>(
        edge_src, edge_dst, offsets, counts, s1, s2, csr_src, csr_e);
    agg_kernel<<<N_NODES / 4, 256, 0, stream>>>(offsets, csr_src, csr_e, z, out);
}

// Round 5
// 349.863 us; speedup vs baseline: 1.5845x; 1.2378x over previous
//
#include <hip/hip_runtime.h>
#include <hip/hip_bf16.h>

#define N_NODES 50000
#define N_EDGES 1000000
#define D_FEAT 512
#define F_ATTN 64
#define SLOPE 0.2f
#define NBLK 196          // ceil(N_NODES / 256)

typedef __attribute__((ext_vector_type(8))) short short8;
typedef __attribute__((ext_vector_type(4))) float floatx4;

// fp32 -> bf16 (round-to-nearest-even), bit trick; inputs are finite randoms.
static __device__ __forceinline__ short f2bf(float x) {
    unsigned u = __float_as_uint(x);
    unsigned r = (u + 0x7FFFu + ((u >> 16) & 1u)) >> 16;
    return (short)r;
}

static __device__ __forceinline__ short8 cvt2(float4 x, float4 y) {
    short8 r;
    r[0] = f2bf(x.x); r[1] = f2bf(x.y); r[2] = f2bf(x.z); r[3] = f2bf(x.w);
    r[4] = f2bf(y.x); r[5] = f2bf(y.y); r[6] = f2bf(y.z); r[7] = f2bf(y.w);
    return r;
}

// async global->LDS, 16B per lane. LDS dest = wave-uniform base + lane*16.
static __device__ __forceinline__ void g2lds16(const void* g, void* l) {
    __builtin_amdgcn_global_load_lds(
        (const __attribute__((address_space(1))) void*)g,
        (__attribute__((address_space(3))) void*)l, 16, 0, 0);
}

// ---------------- One-time W convert: Wd,Wm (64x512 fp32) -> Wb (128x512 bf16)
__global__ __launch_bounds__(256) void wcvt_kernel(
    const float* __restrict__ Wd, const float* __restrict__ Wm,
    short* __restrict__ Wb)
{
    int i = blockIdx.x * 256 + threadIdx.x;           // 0 .. 65535
    int half = F_ATTN * D_FEAT;                        // 32768
    float v = (i < half) ? Wd[i] : Wm[i - half];
    Wb[i] = f2bf(v);
}

// ---------------- Projection + fused attention scalars (m97-style LDS GEMM).
__global__ __launch_bounds__(256) void proj_kernel(
    const float* __restrict__ d_sim,
    const float* __restrict__ m_sim,
    const short* __restrict__ Wb,
    const float* __restrict__ Wa,
    const int* __restrict__ node_type,
    __hip_bfloat16* __restrict__ z,
    float* __restrict__ s1, float* __restrict__ s2)
{
    __shared__ char smem[65536];   // 2 bufs x (16KB A + 16KB B)

    const int w      = threadIdx.x >> 6;
    const int lane   = threadIdx.x & 63;
    const int laneLo = lane & 15;
    const int quad   = lane >> 4;
    const int nodeBase = blockIdx.x * 64;

    // A: instr i stages tile rows w*16+i*4 .. +3; slot = lane&15,
    //    logical chunk = slot ^ (row&7)  (16B = 4 floats)
    const float* aP[4];
    #pragma unroll
    for (int i = 0; i < 4; i++) {
        int r = w * 16 + i * 4 + (lane >> 4);
        int arow = nodeBase + r; if (arow >= N_NODES) arow = N_NODES - 1;
        int lc = (lane & 15) ^ (r & 7);
        const float* src = (node_type[arow] == 1) ? d_sim : m_sim;
        aP[i] = src + (size_t)arow * D_FEAT + (lc << 2);
    }
    // B: instr i stages Wb rows (w*4+i)*8 .. +7; slot = lane&7,
    //    logical chunk = slot ^ (row&7)  (16B = 8 shorts)
    const short* bP[4];
    #pragma unroll
    for (int i = 0; i < 4; i++) {
        int r = (w * 4 + i) * 8 + (lane >> 3);
        int lc = (lane & 7) ^ (r & 7);
        bP[i] = Wb + (size_t)r * D_FEAT + (lc << 3);
    }

    floatx4 accD[4], accM[4];
    #pragma unroll
    for (int nt = 0; nt < 4; nt++) {
        accD[nt] = (floatx4){0.f, 0.f, 0.f, 0.f};
        accM[nt] = (floatx4){0.f, 0.f, 0.f, 0.f};
    }

    {
        char* b0 = smem;
        #pragma unroll
        for (int i = 0; i < 4; i++)
            g2lds16(aP[i], b0 + (w * 16 + i * 4) * 256);
        #pragma unroll
        for (int i = 0; i < 4; i++)
            g2lds16(bP[i], b0 + 16384 + (w * 4 + i) * 1024);
    }
    __syncthreads();

    const int rA  = w * 16 + laneLo;
    const int rx  = laneLo & 7;

    for (int t = 0; t < 8; t++) {
        if (t < 7) {
            char* nb = smem + ((t + 1) & 1) * 32768;
            int k0 = (t + 1) * 64;
            #pragma unroll
            for (int i = 0; i < 4; i++)
                g2lds16(aP[i] + k0, nb + (w * 16 + i * 4) * 256);
            #pragma unroll
            for (int i = 0; i < 4; i++)
                g2lds16(bP[i] + k0, nb + 16384 + (w * 4 + i) * 1024);
        }
        const char* cb = smem + (t & 1) * 32768;
        #pragma unroll
        for (int ks = 0; ks < 2; ks++) {
            int c0 = ks * 8 + quad * 2;
            float4 a0 = *(const float4*)(cb + rA * 256 + ((c0 ^ rx) << 4));
            float4 a1 = *(const float4*)(cb + rA * 256 + (((c0 + 1) ^ rx) << 4));
            short8 a = cvt2(a0, a1);
            int ch = ks * 4 + quad;
            int sl = (ch ^ rx) << 4;
            #pragma unroll
            for (int nt = 0; nt < 4; nt++) {
                const char* rowD = cb + 16384 + (nt * 16 + laneLo) * 128;
                short8 bD = *(const short8*)(rowD + sl);
                short8 bM = *(const short8*)(rowD + 64 * 128 + sl);
                accD[nt] = __builtin_amdgcn_mfma_f32_16x16x32_bf16(a, bD, accD[nt], 0, 0, 0);
                accM[nt] = __builtin_amdgcn_mfma_f32_16x16x32_bf16(a, bM, accM[nt], 0, 0, 0);
            }
        }
        __syncthreads();
    }

    float wa1[4], wa2[4];
    #pragma unroll
    for (int nt = 0; nt < 4; nt++) {
        wa1[nt] = Wa[nt * 16 + laneLo];
        wa2[nt] = Wa[F_ATTN + nt * 16 + laneLo];
    }

    // C/D layout: col = lane&15 (feature), row = quad*4 + reg (node)
    #pragma unroll
    for (int reg = 0; reg < 4; reg++) {
        int node = nodeBase + w * 16 + quad * 4 + reg;
        bool ok = node < N_NODES;
        int isD = ok ? (node_type[node] == 1) : 0;
        float p1 = 0.f, p2 = 0.f;
        #pragma unroll
        for (int nt = 0; nt < 4; nt++) {
            float v = isD ? accD[nt][reg] : accM[nt][reg];
            if (ok) z[(size_t)node * F_ATTN + nt * 16 + laneLo] = __float2bfloat16(v);
            p1 += v * wa1[nt];
            p2 += v * wa2[nt];
        }
        #pragma unroll
        for (int off = 8; off; off >>= 1) {
            p1 += __shfl_xor(p1, off);
            p2 += __shfl_xor(p2, off);
        }
        if (ok && laneLo == 0) { s1[node] = p1; s2[node] = p2; }
    }
}

// ---------------- CSR build: histogram over dst
__global__ __launch_bounds__(256) void hist_kernel(
    const int* __restrict__ edge_dst, int* __restrict__ counts)
{
    int e = blockIdx.x * 256 + threadIdx.x;
    if (e < N_EDGES) atomicAdd(&counts[edge_dst[e]], 1);
}

// ---------------- Hierarchical scan, phase 1: per-block exclusive scan.
// offsets[i] = exclusive prefix within block; bsum[b] = block total.
__global__ __launch_bounds__(256) void scan1_kernel(
    const int* __restrict__ counts, int* __restrict__ offsets,
    int* __restrict__ bsum)
{
    __shared__ int lds[256];
    int t = threadIdx.x;
    int i = blockIdx.x * 256 + t;
    int c = (i < N_NODES) ? counts[i] : 0;
    lds[t] = c;
    __syncthreads();
    for (int off = 1; off < 256; off <<= 1) {
        int u = 0;
        if (t >= off) u = lds[t - off];
        __syncthreads();
        if (t >= off) lds[t] += u;
        __syncthreads();
    }
    if (i < N_NODES) offsets[i] = lds[t] - c;   // exclusive, no base
    if (t == 255) bsum[blockIdx.x] = lds[255];
}

// ---------------- Phase 2: single block scans the 196 block sums.
__global__ __launch_bounds__(256) void scan2_kernel(
    const int* __restrict__ bsum, int* __restrict__ bbase,
    int* __restrict__ offsets)
{
    __shared__ int lds[256];
    int t = threadIdx.x;
    int v = (t < NBLK) ? bsum[t] : 0;
    lds[t] = v;
    __syncthreads();
    for (int off = 1; off < 256; off <<= 1) {
        int u = 0;
        if (t >= off) u = lds[t - off];
        __syncthreads();
        if (t >= off) lds[t] += u;
        __syncthreads();
    }
    if (t < NBLK) bbase[t] = lds[t] - v;        // exclusive base per block
    if (t == 255) offsets[N_NODES] = lds[255];  // total = N_EDGES
}

// ---------------- Phase 3: add block bases.
__global__ __launch_bounds__(256) void scan3_kernel(
    int* __restrict__ offsets, const int* __restrict__ bbase)
{
    int i = blockIdx.x * 256 + threadIdx.x;
    if (i < N_NODES) offsets[i] += bbase[blockIdx.x];
}

// ---------------- Scatter: CSR (src, exp-logit) pairs as one int2 store.
// exp(leaky_relu(s1+s2)) cannot overflow (logits O(1)); softmax ratio is
// identical without the max shift. Reuses counts as cursor (atomicSub
// drains it back to zero).
__global__ __launch_bounds__(256) void scatter_kernel(
    const int* __restrict__ edge_src, const int* __restrict__ edge_dst,
    const int* __restrict__ offsets, int* __restrict__ counts,
    const float* __restrict__ s1, const float* __restrict__ s2,
    int2* __restrict__ csr_we)
{
    int e = blockIdx.x * 256 + threadIdx.x;
    if (e < N_EDGES) {
        int d = edge_dst[e];
        int s = edge_src[e];
        float t = s1[s] + s2[d];
        float ev = (t > 0.f) ? t : SLOPE * t;
        int old = atomicSub(&counts[d], 1);
        int pos = offsets[d] + old - 1;
        int2 we; we.x = s; we.y = __float_as_int(__expf(ev));
        csr_we[pos] = we;
    }
}

// ---------------- Aggregation: one wave per dst node, lane = feature.
// Weights precomputed in scatter. Per-wave LDS staging of (w,src) kills the
// shfl dependency chain; 8-deep unroll keeps 8 z-row gathers outstanding.
__global__ __launch_bounds__(256) void agg_kernel(
    const int* __restrict__ offsets, const int2* __restrict__ csr_we,
    const __hip_bfloat16* __restrict__ z, float* __restrict__ out)
{
    __shared__ float sW[256];
    __shared__ int   sS[256];
    int wv   = threadIdx.x >> 6;
    int lane = threadIdx.x & 63;
    int node = blockIdx.x * 4 + wv;
    int beg = offsets[node], end = offsets[node + 1];
    int wbase = wv * 64;

    float l = 0.f, h = 0.f;
    for (int base = beg; base < end; base += 64) {
        int idx = base + lane;
        int2 we = {0, 0};                       // float bits of 0.0f
        if (idx < end) we = csr_we[idx];
        float wgt = __int_as_float(we.y);
        l += wgt;
        sW[wbase + lane] = wgt;
        sS[wbase + lane] = we.x;
        int cnt = end - base; if (cnt > 64) cnt = 64;
        for (int j = 0; j < cnt; j += 8) {
            #pragma unroll
            for (int u = 0; u < 8; u++) {       // slots >= cnt have w=0 (pad)
                float wj = sW[wbase + j + u];
                int   sj = sS[wbase + j + u];
                h += wj * __bfloat162float(z[(size_t)sj * F_ATTN + lane]);
            }
        }
    }
    #pragma unroll
    for (int off = 32; off; off >>= 1) l += __shfl_xor(l, off);

    float hv = (end > beg) ? h / l : 0.f;
    float o  = (hv > 0.f) ? hv : (__expf(hv) - 1.f);   // elu
    out[(size_t)node * F_ATTN + lane] = o;
}

extern "C" void kernel_launch(void* const* d_in, const int* in_sizes, int n_in,
                              void* d_out, int out_size, void* d_ws, size_t ws_size,
                              hipStream_t stream) {
    const float* d_sim = (const float*)d_in[0];
    const float* m_sim = (const float*)d_in[1];
    const float* Wd    = (const float*)d_in[2];
    const float* Wm    = (const float*)d_in[3];
    const float* Wa    = (const float*)d_in[4];
    const int* node_type = (const int*)d_in[5];
    const int* edge_src  = (const int*)d_in[6];
    const int* edge_dst  = (const int*)d_in[7];
    float* out = (float*)d_out;

    char* ws = (char*)d_ws;
    // ws layout (bytes):
    __hip_bfloat16* z  = (__hip_bfloat16*)(ws + 0);        //  6,400,000
    float* s1          = (float*)(ws + 6400000);           //    200,000
    float* s2          = (float*)(ws + 6600000);           //    200,000
    int*   counts      = (int*)  (ws + 6800000);           //    200,000
    int*   offsets     = (int*)  (ws + 7000000);           //    200,016
    int*   bsum        = (int*)  (ws + 7200016);           //      1,024
    int*   bbase       = (int*)  (ws + 7201040);           //      1,024
    int2*  csr_we      = (int2*) (ws + 7202064);           //  8,000,000 (8B aligned)
    short* Wb          = (short*)(ws + 15202064);          //    131,072 (16B aligned)

    hipMemsetAsync(counts, 0, N_NODES * sizeof(int), stream);

    wcvt_kernel<<<(2 * F_ATTN * D_FEAT) / 256, 256, 0, stream>>>(Wd, Wm, Wb);
    proj_kernel<<<(N_NODES + 63) / 64, 256, 0, stream>>>(
        d_sim, m_sim, Wb, Wa, node_type, z, s1, s2);
    hist_kernel<<<(N_EDGES + 255) / 256, 256, 0, stream>>>(edge_dst, counts);
    scan1_kernel<<<NBLK, 256, 0, stream>>>(counts, offsets, bsum);
    scan2_kernel<<<1, 256, 0, stream>>>(bsum, bbase, offsets);
    scan3_kernel<<<NBLK, 256, 0, stream>>>(offsets, bbase);
    scatter_kernel<<<(N_EDGES + 255) / 256, 256, 0, stream>>>(
        edge_src, edge_dst, offsets, counts, s1, s2, csr_we);
    agg_kernel<<<N_NODES / 4, 256, 0, stream>>>(offsets, csr_we, z, out);
}

// Round 6
// 324.771 us; speedup vs baseline: 1.7069x; 1.0773x over previous
//
#include <hip/hip_runtime.h>
#include <hip/hip_bf16.h>

#define N_NODES 50000
#define N_EDGES 1000000
#define D_FEAT 512
#define F_ATTN 64
#define SLOPE 0.2f
#define NBLK 196          // ceil(N_NODES / 256)

typedef __attribute__((ext_vector_type(8))) short short8;
typedef __attribute__((ext_vector_type(4))) float floatx4;

// fp32 -> bf16 (round-to-nearest-even), bit trick; inputs are finite randoms.
static __device__ __forceinline__ short f2bf(float x) {
    unsigned u = __float_as_uint(x);
    unsigned r = (u + 0x7FFFu + ((u >> 16) & 1u)) >> 16;
    return (short)r;
}

static __device__ __forceinline__ short8 cvt2(float4 x, float4 y) {
    short8 r;
    r[0] = f2bf(x.x); r[1] = f2bf(x.y); r[2] = f2bf(x.z); r[3] = f2bf(x.w);
    r[4] = f2bf(y.x); r[5] = f2bf(y.y); r[6] = f2bf(y.z); r[7] = f2bf(y.w);
    return r;
}

static __device__ __forceinline__ float bfu2f(unsigned short v) {
    return __uint_as_float((unsigned)v << 16);
}

// async global->LDS, 16B per lane. LDS dest = wave-uniform base + lane*16.
static __device__ __forceinline__ void g2lds16(const void* g, void* l) {
    __builtin_amdgcn_global_load_lds(
        (const __attribute__((address_space(1))) void*)g,
        (__attribute__((address_space(3))) void*)l, 16, 0, 0);
}

// ---------------- One-time W convert: Wd,Wm (64x512 fp32) -> Wb (128x512 bf16)
__global__ __launch_bounds__(256) void wcvt_kernel(
    const float* __restrict__ Wd, const float* __restrict__ Wm,
    short* __restrict__ Wb)
{
    int i = blockIdx.x * 256 + threadIdx.x;           // 0 .. 65535
    int half = F_ATTN * D_FEAT;                        // 32768
    float v = (i < half) ? Wd[i] : Wm[i - half];
    Wb[i] = f2bf(v);
}

// ---------------- Projection + fused attention scalars (m97-style LDS GEMM).
__global__ __launch_bounds__(256) void proj_kernel(
    const float* __restrict__ d_sim,
    const float* __restrict__ m_sim,
    const short* __restrict__ Wb,
    const float* __restrict__ Wa,
    const int* __restrict__ node_type,
    __hip_bfloat16* __restrict__ z,
    float* __restrict__ s1, float* __restrict__ s2)
{
    __shared__ char smem[65536];   // 2 bufs x (16KB A + 16KB B)

    const int w      = threadIdx.x >> 6;
    const int lane   = threadIdx.x & 63;
    const int laneLo = lane & 15;
    const int quad   = lane >> 4;
    const int nodeBase = blockIdx.x * 64;

    // A: instr i stages tile rows w*16+i*4 .. +3; slot = lane&15,
    //    logical chunk = slot ^ (row&7)  (16B = 4 floats)
    const float* aP[4];
    #pragma unroll
    for (int i = 0; i < 4; i++) {
        int r = w * 16 + i * 4 + (lane >> 4);
        int arow = nodeBase + r; if (arow >= N_NODES) arow = N_NODES - 1;
        int lc = (lane & 15) ^ (r & 7);
        const float* src = (node_type[arow] == 1) ? d_sim : m_sim;
        aP[i] = src + (size_t)arow * D_FEAT + (lc << 2);
    }
    // B: instr i stages Wb rows (w*4+i)*8 .. +7; slot = lane&7,
    //    logical chunk = slot ^ (row&7)  (16B = 8 shorts)
    const short* bP[4];
    #pragma unroll
    for (int i = 0; i < 4; i++) {
        int r = (w * 4 + i) * 8 + (lane >> 3);
        int lc = (lane & 7) ^ (r & 7);
        bP[i] = Wb + (size_t)r * D_FEAT + (lc << 3);
    }

    floatx4 accD[4], accM[4];
    #pragma unroll
    for (int nt = 0; nt < 4; nt++) {
        accD[nt] = (floatx4){0.f, 0.f, 0.f, 0.f};
        accM[nt] = (floatx4){0.f, 0.f, 0.f, 0.f};
    }

    {
        char* b0 = smem;
        #pragma unroll
        for (int i = 0; i < 4; i++)
            g2lds16(aP[i], b0 + (w * 16 + i * 4) * 256);
        #pragma unroll
        for (int i = 0; i < 4; i++)
            g2lds16(bP[i], b0 + 16384 + (w * 4 + i) * 1024);
    }
    __syncthreads();

    const int rA  = w * 16 + laneLo;
    const int rx  = laneLo & 7;

    for (int t = 0; t < 8; t++) {
        if (t < 7) {
            char* nb = smem + ((t + 1) & 1) * 32768;
            int k0 = (t + 1) * 64;
            #pragma unroll
            for (int i = 0; i < 4; i++)
                g2lds16(aP[i] + k0, nb + (w * 16 + i * 4) * 256);
            #pragma unroll
            for (int i = 0; i < 4; i++)
                g2lds16(bP[i] + k0, nb + 16384 + (w * 4 + i) * 1024);
        }
        const char* cb = smem + (t & 1) * 32768;
        #pragma unroll
        for (int ks = 0; ks < 2; ks++) {
            int c0 = ks * 8 + quad * 2;
            float4 a0 = *(const float4*)(cb + rA * 256 + ((c0 ^ rx) << 4));
            float4 a1 = *(const float4*)(cb + rA * 256 + (((c0 + 1) ^ rx) << 4));
            short8 a = cvt2(a0, a1);
            int ch = ks * 4 + quad;
            int sl = (ch ^ rx) << 4;
            #pragma unroll
            for (int nt = 0; nt < 4; nt++) {
                const char* rowD = cb + 16384 + (nt * 16 + laneLo) * 128;
                short8 bD = *(const short8*)(rowD + sl);
                short8 bM = *(const short8*)(rowD + 64 * 128 + sl);
                accD[nt] = __builtin_amdgcn_mfma_f32_16x16x32_bf16(a, bD, accD[nt], 0, 0, 0);
                accM[nt] = __builtin_amdgcn_mfma_f32_16x16x32_bf16(a, bM, accM[nt], 0, 0, 0);
            }
        }
        __syncthreads();
    }

    float wa1[4], wa2[4];
    #pragma unroll
    for (int nt = 0; nt < 4; nt++) {
        wa1[nt] = Wa[nt * 16 + laneLo];
        wa2[nt] = Wa[F_ATTN + nt * 16 + laneLo];
    }

    // C/D layout: col = lane&15 (feature), row = quad*4 + reg (node)
    #pragma unroll
    for (int reg = 0; reg < 4; reg++) {
        int node = nodeBase + w * 16 + quad * 4 + reg;
        bool ok = node < N_NODES;
        int isD = ok ? (node_type[node] == 1) : 0;
        float p1 = 0.f, p2 = 0.f;
        #pragma unroll
        for (int nt = 0; nt < 4; nt++) {
            float v = isD ? accD[nt][reg] : accM[nt][reg];
            if (ok) z[(size_t)node * F_ATTN + nt * 16 + laneLo] = __float2bfloat16(v);
            p1 += v * wa1[nt];
            p2 += v * wa2[nt];
        }
        #pragma unroll
        for (int off = 8; off; off >>= 1) {
            p1 += __shfl_xor(p1, off);
            p2 += __shfl_xor(p2, off);
        }
        if (ok && laneLo == 0) { s1[node] = p1; s2[node] = p2; }
    }
}

// ---------------- CSR build: histogram over dst + per-edge rank capture.
// rank[e] = this edge's arrival index within its dst bucket (coalesced write);
// scatter then needs NO atomic at all.
__global__ __launch_bounds__(256) void hist_kernel(
    const int* __restrict__ edge_dst, int* __restrict__ counts,
    int* __restrict__ rank)
{
    int e = blockIdx.x * 256 + threadIdx.x;
    if (e < N_EDGES) rank[e] = atomicAdd(&counts[edge_dst[e]], 1);
}

// ---------------- Hierarchical scan, phase 1: per-block exclusive scan.
// Writes indices i <= N_NODES (50000 < 196*256) WITHOUT the block base;
// consumers add bbase[i>>8]. bsum[b] = block total.
__global__ __launch_bounds__(256) void scan1_kernel(
    const int* __restrict__ counts, int* __restrict__ offsets,
    int* __restrict__ bsum)
{
    __shared__ int lds[256];
    int t = threadIdx.x;
    int i = blockIdx.x * 256 + t;
    int c = (i < N_NODES) ? counts[i] : 0;
    lds[t] = c;
    __syncthreads();
    for (int off = 1; off < 256; off <<= 1) {
        int u = 0;
        if (t >= off) u = lds[t - off];
        __syncthreads();
        if (t >= off) lds[t] += u;
        __syncthreads();
    }
    if (i <= N_NODES) offsets[i] = lds[t] - c;   // exclusive, no base
    if (t == 255) bsum[blockIdx.x] = lds[255];
}

// ---------------- Phase 2: single block scans the 196 block sums.
__global__ __launch_bounds__(256) void scan2_kernel(
    const int* __restrict__ bsum, int* __restrict__ bbase)
{
    __shared__ int lds[256];
    int t = threadIdx.x;
    int v = (t < NBLK) ? bsum[t] : 0;
    lds[t] = v;
    __syncthreads();
    for (int off = 1; off < 256; off <<= 1) {
        int u = 0;
        if (t >= off) u = lds[t - off];
        __syncthreads();
        if (t >= off) lds[t] += u;
        __syncthreads();
    }
    if (t < NBLK) bbase[t] = lds[t] - v;        // exclusive base per block
}

// ---------------- Scatter: CSR (src, exp-logit) pairs, atomic-free.
// pos = offsets[d] + bbase[d>>8] + rank[e]. exp(leaky) can't overflow
// (logits O(1)); softmax ratio identical without the max shift.
__global__ __launch_bounds__(256) void scatter_kernel(
    const int* __restrict__ edge_src, const int* __restrict__ edge_dst,
    const int* __restrict__ offsets, const int* __restrict__ bbase,
    const int* __restrict__ rank,
    const float* __restrict__ s1, const float* __restrict__ s2,
    int2* __restrict__ csr_we)
{
    int e = blockIdx.x * 256 + threadIdx.x;
    if (e < N_EDGES) {
        int d = edge_dst[e];
        int s = edge_src[e];
        float t = s1[s] + s2[d];
        float ev = (t > 0.f) ? t : SLOPE * t;
        int pos = offsets[d] + bbase[d >> 8] + rank[e];
        int2 we; we.x = s; we.y = __float_as_int(__expf(ev));
        csr_we[pos] = we;
    }
}

// ---------------- Aggregation: one wave per dst node.
// Lane layout: 16 lanes x 4 features (ushort4 = 8B) per edge, 4 edges per
// VMEM instruction -> 4 cache lines in flight per instr, 16 instrs per
// 64-edge chunk (vs 64 before). float4 accumulators; slot groups combined
// with shfl_xor(16,32); lanes 0-15 store float4 (256B per node).
__global__ __launch_bounds__(256) void agg_kernel(
    const int* __restrict__ offsets, const int* __restrict__ bbase,
    const int2* __restrict__ csr_we,
    const __hip_bfloat16* __restrict__ z, float* __restrict__ out)
{
    __shared__ float sW[256];
    __shared__ int   sS[256];
    int wv   = threadIdx.x >> 6;
    int lane = threadIdx.x & 63;
    int node = blockIdx.x * 4 + wv;
    int beg = offsets[node]     + bbase[node >> 8];
    int end = offsets[node + 1] + bbase[(node + 1) >> 8];
    int wbase = wv * 64;
    int fgrp  = (lane & 15) * 4;    // this lane's 4 features
    int ep    = lane >> 4;          // edge-slot offset 0..3

    float4 h = {0.f, 0.f, 0.f, 0.f};
    float l = 0.f;
    for (int base = beg; base < end; base += 64) {
        int idx = base + lane;
        int2 we = {0, 0};                       // float bits of 0.0f
        if (idx < end) we = csr_we[idx];
        float wgt = __int_as_float(we.y);
        l += wgt;
        sW[wbase + lane] = wgt;                 // wave-private: no barrier
        sS[wbase + lane] = we.x;
        int cnt = end - base; if (cnt > 64) cnt = 64;
        for (int j = 0; j < cnt; j += 16) {     // sW/sS fully written: j+15<64 safe
            #pragma unroll
            for (int u = 0; u < 16; u += 4) {   // pad slots have w=0
                int slot = wbase + j + u + ep;
                float wj = sW[slot];
                int   sj = sS[slot];
                ushort4 zz = *(const ushort4*)((const unsigned short*)z +
                                               (size_t)sj * F_ATTN + fgrp);
                h.x += wj * bfu2f(zz.x);
                h.y += wj * bfu2f(zz.y);
                h.z += wj * bfu2f(zz.z);
                h.w += wj * bfu2f(zz.w);
            }
        }
    }
    // combine the 4 edge-slot groups (lanes differing in bits 4,5)
    #pragma unroll
    for (int off = 16; off <= 32; off <<= 1) {
        h.x += __shfl_xor(h.x, off);
        h.y += __shfl_xor(h.y, off);
        h.z += __shfl_xor(h.z, off);
        h.w += __shfl_xor(h.w, off);
    }
    #pragma unroll
    for (int off = 32; off; off >>= 1) l += __shfl_xor(l, off);

    if (ep == 0) {
        float inv = (end > beg) ? 1.f / l : 0.f;
        float4 o;
        float v;
        v = h.x * inv; o.x = (v > 0.f) ? v : (__expf(v) - 1.f);
        v = h.y * inv; o.y = (v > 0.f) ? v : (__expf(v) - 1.f);
        v = h.z * inv; o.z = (v > 0.f) ? v : (__expf(v) - 1.f);
        v = h.w * inv; o.w = (v > 0.f) ? v : (__expf(v) - 1.f);
        *(float4*)(out + (size_t)node * F_ATTN + fgrp) = o;
    }
}

extern "C" void kernel_launch(void* const* d_in, const int* in_sizes, int n_in,
                              void* d_out, int out_size, void* d_ws, size_t ws_size,
                              hipStream_t stream) {
    const float* d_sim = (const float*)d_in[0];
    const float* m_sim = (const float*)d_in[1];
    const float* Wd    = (const float*)d_in[2];
    const float* Wm    = (const float*)d_in[3];
    const float* Wa    = (const float*)d_in[4];
    const int* node_type = (const int*)d_in[5];
    const int* edge_src  = (const int*)d_in[6];
    const int* edge_dst  = (const int*)d_in[7];
    float* out = (float*)d_out;

    char* ws = (char*)d_ws;
    // ws layout (bytes):
    __hip_bfloat16* z  = (__hip_bfloat16*)(ws + 0);        //  6,400,000
    float* s1          = (float*)(ws + 6400000);           //    200,000
    float* s2          = (float*)(ws + 6600000);           //    200,000
    int*   counts      = (int*)  (ws + 6800000);           //    200,000
    int*   offsets     = (int*)  (ws + 7000000);           //    200,016
    int*   bsum        = (int*)  (ws + 7200016);           //      1,024
    int*   bbase       = (int*)  (ws + 7201040);           //      1,024
    int2*  csr_we      = (int2*) (ws + 7202064);           //  8,000,000 (8B aligned)
    short* Wb          = (short*)(ws + 15202064);          //    131,072 (16B aligned)
    int*   rank        = (int*)  (ws + 15333136);          //  4,000,000

    hipMemsetAsync(counts, 0, N_NODES * sizeof(int), stream);

    wcvt_kernel<<<(2 * F_ATTN * D_FEAT) / 256, 256, 0, stream>>>(Wd, Wm, Wb);
    proj_kernel<<<(N_NODES + 63) / 64, 256, 0, stream>>>(
        d_sim, m_sim, Wb, Wa, node_type, z, s1, s2);
    hist_kernel<<<(N_EDGES + 255) / 256, 256, 0, stream>>>(edge_dst, counts, rank);
    scan1_kernel<<<NBLK, 256, 0, stream>>>(counts, offsets, bsum);
    scan2_kernel<<<1, 256, 0, stream>>>(bsum, bbase);
    scatter_kernel<<<(N_EDGES + 255) / 256, 256, 0, stream>>>(
        edge_src, edge_dst, offsets, bbase, rank, s1, s2, csr_we);
    agg_kernel<<<N_NODES / 4, 256, 0, stream>>>(offsets, bbase, csr_we, z, out);
}